// Round 5
// baseline (986.843 us; speedup 1.0000x reference)
//
#include <hip/hip_runtime.h>
#include <stdint.h>

// Problem constants (B,T,C,H,N) = (4,960,2048,32,64)
#define BDIM 4
#define TDIM 960
#define CDIM 2048
#define HDIM 32
#define NDIM 64
#define BT   (BDIM*TDIM)   // 3840 rows

typedef unsigned short u16;
typedef __attribute__((ext_vector_type(8))) short short8;   // 8 bf16 (4 VGPRs)
typedef __attribute__((ext_vector_type(4))) float f32x4;

__device__ __forceinline__ float b2f(u16 u){
  union{unsigned int i; float f;}x; x.i=((unsigned int)u)<<16; return x.f;
}
__device__ __forceinline__ u16 f2b(float f){
  union{float f; unsigned int i;}x; x.f=f;
  unsigned int r = x.i + 0x7fffu + ((x.i>>16)&1u);   // RNE
  return (u16)(r>>16);
}
__device__ __forceinline__ unsigned pk2(float lo, float hi){
  return (unsigned)f2b(lo) | ((unsigned)f2b(hi)<<16);
}
__device__ __forceinline__ void unpack8(uint4 p, float* o){
  o[0]=b2f((u16)(p.x&0xffff)); o[1]=b2f((u16)(p.x>>16));
  o[2]=b2f((u16)(p.y&0xffff)); o[3]=b2f((u16)(p.y>>16));
  o[4]=b2f((u16)(p.z&0xffff)); o[5]=b2f((u16)(p.z>>16));
  o[6]=b2f((u16)(p.w&0xffff)); o[7]=b2f((u16)(p.w>>16));
}
__device__ __forceinline__ uint4 pack8(const float* o){
  uint4 p;
  p.x = pk2(o[0],o[1]);
  p.y = pk2(o[2],o[3]);
  p.z = pk2(o[4],o[5]);
  p.w = pk2(o[6],o[7]);
  return p;
}
__device__ __forceinline__ void ld8f(const float* p, float* o){
  float4 a = *(const float4*)p;
  float4 b = *(const float4*)(p+4);
  o[0]=a.x;o[1]=a.y;o[2]=a.z;o[3]=a.w;o[4]=b.x;o[5]=b.y;o[6]=b.z;o[7]=b.w;
}
__device__ __forceinline__ float sigm(float x){ return 1.f/(1.f+expf(-x)); }
__device__ __forceinline__ void stc(float* p, float v){ *p = v; }
__device__ __forceinline__ void stc(u16* p, float v){ *p = f2b(v); }

// 16-lane butterfly sum on the VALU pipe (DPP), zero LDS traffic.
// Stages: xor1 = quad_perm[1,0,3,2] (0xB1), xor2 = quad_perm[2,3,0,1] (0x4E),
// then row_half_mirror (0x141) and row_mirror (0x140) — after the first two
// stages each quad/8-group is uniform, so mirror == xor4/xor8.
__device__ __forceinline__ float row_red16(float x){
  x += __int_as_float(__builtin_amdgcn_update_dpp(0, __float_as_int(x), 0xB1,  0xF, 0xF, true));
  x += __int_as_float(__builtin_amdgcn_update_dpp(0, __float_as_int(x), 0x4E,  0xF, 0xF, true));
  x += __int_as_float(__builtin_amdgcn_update_dpp(0, __float_as_int(x), 0x141, 0xF, 0xF, true));
  x += __int_as_float(__builtin_amdgcn_update_dpp(0, __float_as_int(x), 0x140, 0xF, 0xF, true));
  return x;
}
// cross-16 exchange (lane ^ 16) via ds_swizzle bitmode: xor=16,or=0,and=0x1F
__device__ __forceinline__ float xor16(float x){
  return __int_as_float(__builtin_amdgcn_ds_swizzle(__float_as_int(x), 0x401F));
}

// ---------------------------------------------------------------------------
// 0) fp32 -> bf16 weight conversion (one 2048x2048 matrix per launch)
__global__ __launch_bounds__(256) void cvt_kernel(const float* src, u16* dst){
  size_t i = ((size_t)blockIdx.x*256 + threadIdx.x)*8;
  float v[8]; ld8f(src+i, v);
  *(uint4*)(dst+i) = pack8(v);
}

// ---------------------------------------------------------------------------
// 1) batched transpose+pad+cvt for LoRA weights (tiny: <6 MB total)
// dst[i][k] = (i<Cs && k<R) ? src[k][i] : 0   with dst dims DR x DC
struct TJob { const float* src; u16* dst; int R, Cs, DR, DC; };
struct TJobs8 { TJob j[8]; };

__global__ __launch_bounds__(256) void transpose_pad_kernel(TJobs8 jobs){
  TJob jb = jobs.j[blockIdx.z];
  int idx = blockIdx.x*256 + threadIdx.x;
  int total = jb.DR*jb.DC;
  if (idx >= total) return;
  int i = idx / jb.DC, k = idx % jb.DC;
  float v = 0.f;
  if (i < jb.Cs && k < jb.R) v = jb.src[(size_t)k*jb.Cs + i];
  jb.dst[idx] = f2b(v);
}

// ---------------------------------------------------------------------------
// 2) token-shift mixes: m = x + (x_prev - x)*coef  (6 bf16 outputs)
__global__ __launch_bounds__(256) void mix_kernel(
  const float* x,
  const float* cr, const float* cw, const float* ck,
  const float* cv, const float* ca, const float* cg,
  u16* mr, u16* mw, u16* mk, u16* mv, u16* ma, u16* mg)
{
  size_t tid = (size_t)blockIdx.x*256 + threadIdx.x;
  size_t base = tid*8;
  int c = (int)(base % CDIM);
  int row = (int)(base / CDIM);
  int t = row % TDIM;
  float xc[8], xp[8], xx[8], cf[8], o[8];
  ld8f(x+base, xc);
  if (t > 0) {
    ld8f(x+base-CDIM, xp);
  } else {
    for(int j=0;j<8;j++) xp[j]=0.f;
  }
  #pragma unroll
  for(int j=0;j<8;j++) xx[j]=xp[j]-xc[j];
#define DOMIX(CP, OP) do { ld8f(CP+c, cf); \
  _Pragma("unroll") for(int j=0;j<8;j++) o[j]=xc[j]+xx[j]*cf[j]; \
  *(uint4*)(OP+base)=pack8(o); } while(0)
  DOMIX(cr, mr); DOMIX(cw, mw); DOMIX(ck, mk);
  DOMIX(cv, mv); DOMIX(ca, ma); DOMIX(cg, mg);
#undef DOMIX
}

// ---------------------------------------------------------------------------
// 3) bf16 GEMM, C[M,N] = A[M,K] * Bt[N,K]^T  (B^T layout, m97 structure)
// 128x128 tile, BK=64, 256 threads (2x2 waves, each 64x64 = 4x4 MFMA 16x16x32)
// C store dtype templated (fp32 or bf16).
struct GemmJob {
  const u16* A; const u16* Bt; void* C;
  int nbm, nbn, K, lda, ldb, ldc;
};
struct GemmJobs { GemmJob j[4]; };

template<typename TC>
__global__ __launch_bounds__(256, 2) void gemm_bt_kernel(GemmJobs jobs){
  GemmJob jb = jobs.j[blockIdx.z];
  int bm = blockIdx.x % jb.nbm;
  int bn = blockIdx.x / jb.nbm;
  if (bn >= jb.nbn) return;
  __shared__ __attribute__((aligned(16))) u16 As[128*64];
  __shared__ __attribute__((aligned(16))) u16 Bs[128*64];
  int tid = threadIdx.x;
  int wave = tid>>6, lane = tid&63;
  int wr = wave>>1, wc = wave&1;
  f32x4 acc[4][4];
  #pragma unroll
  for(int i=0;i<4;i++)
    #pragma unroll
    for(int j=0;j<4;j++) acc[i][j] = (f32x4){0.f,0.f,0.f,0.f};
  const int rA0 = bm*128;
  const int rB0 = bn*128;
  int srow = (lane>>3);        // 0..7 row within 8-row slab
  int scol = (lane&7)*8;       // k element offset (8 bf16 = 16B)
  for (int k0=0; k0<jb.K; k0+=64){
    #pragma unroll
    for (int it=0; it<4; ++it){
      int rr = wave*32 + it*8;  // wave-uniform
      const u16* gA = jb.A + (size_t)(rA0 + rr + srow)*jb.lda + (k0 + scol);
      __builtin_amdgcn_global_load_lds((const __attribute__((address_space(1))) void*)gA,
          (__attribute__((address_space(3))) void*)&As[rr*64], 16, 0, 0);
      const u16* gB = jb.Bt + (size_t)(rB0 + rr + srow)*jb.ldb + (k0 + scol);
      __builtin_amdgcn_global_load_lds((const __attribute__((address_space(1))) void*)gB,
          (__attribute__((address_space(3))) void*)&Bs[rr*64], 16, 0, 0);
    }
    __syncthreads();   // compiler emits vmcnt(0) drain before s_barrier
    #pragma unroll
    for (int kc=0; kc<2; ++kc){
      short8 af[4], bfr[4];
      int ko = kc*32 + (lane>>4)*8;
      #pragma unroll
      for (int mi=0; mi<4; ++mi)
        af[mi] = *(const short8*)&As[(wr*64 + mi*16 + (lane&15))*64 + ko];
      #pragma unroll
      for (int ni=0; ni<4; ++ni)
        bfr[ni] = *(const short8*)&Bs[(wc*64 + ni*16 + (lane&15))*64 + ko];
      #pragma unroll
      for (int mi=0; mi<4; ++mi)
        #pragma unroll
        for (int ni=0; ni<4; ++ni)
          acc[mi][ni] = __builtin_amdgcn_mfma_f32_16x16x32_bf16(af[mi], bfr[ni], acc[mi][ni], 0, 0, 0);
    }
    __syncthreads();
  }
  // epilogue: C/D layout col=lane&15, row=(lane>>4)*4+reg  [m89/m91 verified]
  TC* C = (TC*)jb.C;
  int cn = (lane&15);
  int rq = (lane>>4)*4;
  #pragma unroll
  for (int mi=0; mi<4; ++mi){
    #pragma unroll
    for (int ni=0; ni<4; ++ni){
      int col = rB0 + wc*64 + ni*16 + cn;
      int row = rA0 + wr*64 + mi*16 + rq;
      #pragma unroll
      for (int e=0; e<4; ++e)
        stc(&C[(size_t)(row+e)*jb.ldc + col], acc[mi][ni][e]);
    }
  }
}

// ---------------------------------------------------------------------------
// 4) mid-LoRA activations: tanh on hw, sigmoid on hg (pads stay 0 -> tanh(0)=0)
__global__ __launch_bounds__(256) void act_kernel(u16* hw, u16* hg){
  int idx = blockIdx.x*256 + threadIdx.x;
  if (blockIdx.z==0){ if (idx < BT*128) hw[idx] = f2b(tanhf(b2f(hw[idx]))); }
  else              { if (idx < BT*256) hg[idx] = f2b(sigm(b2f(hg[idx]))); }
}

// ---------------------------------------------------------------------------
// 5) post-GEMM elementwise: w decay, a/v finals, kk normalize, k scale
// Outputs for the scan: DECAY fp32, QKI = interleaved {q01,k01} 8B entries
// per colpair, ABI = interleaved {a01,b01}, VS bf16 (written in-place over
// the dead RBUF plane).
__global__ __launch_bounds__(256) void post_kernel(
  const u16* rbuf, const u16* kbuf, const u16* vraw, const float* vfirst,
  const u16* wl, const u16* al, const u16* vl,
  const float* w0, const float* a0, const float* v0,
  const float* kkc, const float* kac,
  float* dout, uint4* qki, uint4* abi, u16* vs)
{
  int row = blockIdx.x, tid = threadIdx.x;
  int c = tid*8;
  size_t base = (size_t)row*CDIM + c;
  float qf[8], kf[8], vr[8], vf[8], wlf[8], alf[8], vlf[8], w0f[8], a0f[8], v0f[8], kkf[8], kaf[8];
  unpack8(*(const uint4*)(rbuf+base), qf);
  unpack8(*(const uint4*)(kbuf+base), kf);
  unpack8(*(const uint4*)(vraw+base), vr);
  ld8f(vfirst+base, vf);
  unpack8(*(const uint4*)(wl+base), wlf);
  unpack8(*(const uint4*)(al+base), alf);
  unpack8(*(const uint4*)(vl+base), vlf);
  ld8f(w0+c, w0f);
  ld8f(a0+c, a0f);
  ld8f(v0+c, v0f);
  ld8f(kkc+c, kkf);
  ld8f(kac+c, kaf);
  float dv[8], av[8], vv[8], kkr[8], kfin[8], asv[8], bsv[8];
  float ssq = 0.f;
  #pragma unroll
  for (int j=0;j<8;j++){
    float wv = -log1pf(expf(-(w0f[j]+wlf[j]))) - 0.5f;       // -softplus(-z)-0.5
    dv[j]  = expf(-expf(wv));                                // decay
    av[j]  = sigm(a0f[j]+alf[j]);
    vv[j]  = vr[j] + (vf[j]-vr[j])*sigm(v0f[j]+vlf[j]);
    kkr[j] = kf[j]*kkf[j];
    ssq   += kkr[j]*kkr[j];
    kfin[j]= kf[j]*(1.f + (av[j]-1.f)*kaf[j]);
  }
  // head = 8 consecutive lanes (thread covers 8 contiguous c, head = 64 c)
  ssq += __shfl_xor(ssq,1); ssq += __shfl_xor(ssq,2); ssq += __shfl_xor(ssq,4);
  float inv = 1.f/fmaxf(sqrtf(ssq), 1e-12f);
  #pragma unroll
  for (int j=0;j<8;j++){ float kkn = kkr[j]*inv; asv[j] = -kkn; bsv[j] = kkn*av[j]; }
  *(float4*)(dout+base)   = make_float4(dv[0],dv[1],dv[2],dv[3]);
  *(float4*)(dout+base+4) = make_float4(dv[4],dv[5],dv[6],dv[7]);
  // interleaved q/k and a/b: 8B entry per colpair, byte off = row*8192 + c*4
  uint4* qke = (uint4*)((char*)qki + (size_t)row*8192 + (size_t)c*4);
  qke[0] = make_uint4(pk2(qf[0],qf[1]), pk2(kfin[0],kfin[1]), pk2(qf[2],qf[3]), pk2(kfin[2],kfin[3]));
  qke[1] = make_uint4(pk2(qf[4],qf[5]), pk2(kfin[4],kfin[5]), pk2(qf[6],qf[7]), pk2(kfin[6],kfin[7]));
  uint4* abe = (uint4*)((char*)abi + (size_t)row*8192 + (size_t)c*4);
  abe[0] = make_uint4(pk2(asv[0],asv[1]), pk2(bsv[0],bsv[1]), pk2(asv[2],asv[3]), pk2(bsv[2],bsv[3]));
  abe[1] = make_uint4(pk2(asv[4],asv[5]), pk2(bsv[4],bsv[5]), pk2(asv[6],asv[7]), pk2(bsv[6],bsv[7]));
  *(uint4*)(vs+base) = pack8(vv);   // vs aliases rbuf: in-thread read-then-write
}

// ---------------------------------------------------------------------------
// 6) the linear recurrence. Rows of S evolve independently:
//    S_t[i,:] = S_{t-1}[i,:]*(diag(d)+a b^T) + v_i k^T
// Round-5: round-3 geometry (1024 blocks, 8 rows/block, 32-lane col groups,
// 2 cols/thread) + round-4's PROVEN pipeline mechanism (8 named 7-VGPR step
// records, refill right after consume, sched_barrier(0) fences). Round 4
// showed 2 waves/SIMD saturates only 72% of issue; this doubles chains/SIMD
// to 4 and halves per-wave step work. 32-lane reduction = 4 DPP stages +
// one ds_swizzle xor-16. Memory layouts identical to round 4 (QKI/ABI uint4
// entries == per-colpair uint2 entries), so post/final are unchanged.
__global__ __launch_bounds__(256, 4) void scan_kernel(
  const float* __restrict__ decayp, const uint2* __restrict__ qki,
  const uint2* __restrict__ abi, const u16* __restrict__ vs,
  float* __restrict__ yb)
{
  int blk = blockIdx.x;          // b*256 + h*8 + oct
  int b   = blk >> 8;
  int h   = (blk >> 3) & 31;
  int oct = blk & 7;
  int tid = threadIdx.x;
  int jg  = tid & 31;            // col pair (2 cols)
  int ii  = tid >> 5;            // row within octant (0..7)
  int row = oct*8 + ii;

  const char* dP = (const char*)decayp + (size_t)b*TDIM*8192 + h*256 + jg*8;
  const char* qP = (const char*)qki    + (size_t)b*TDIM*8192 + h*256 + jg*8;
  const char* aP = (const char*)abi    + (size_t)b*TDIM*8192 + h*256 + jg*8;
  const char* vP = (const char*)vs     + (size_t)b*TDIM*4096 + h*128 + row*2;

  float Sx=0.f, Sy=0.f;

  struct SR { float2 d; uint2 qk; uint2 ab; u16 v; };   // 7 VGPRs
  auto ld = [&](int t)->SR{
    SR r; size_t o = (size_t)t*8192;
    r.d  = *(const float2*)(dP + o);
    r.qk = *(const uint2*)(qP + o);
    r.ab = *(const uint2*)(aP + o);
    r.v  = *(const u16*)(vP + (size_t)t*4096);
    return r;
  };
  auto dostep = [&](const SR& r)->float{
    float aLo=b2f((u16)(r.ab.x&0xffff)), aHi=b2f((u16)(r.ab.x>>16));
    float sap = Sx*aLo + Sy*aHi;
    sap = row_red16(sap);
    sap += xor16(sap);                         // cross-16 (lane^16) exchange
    float bLo=b2f((u16)(r.ab.y&0xffff)), bHi=b2f((u16)(r.ab.y>>16));
    float kLo=b2f((u16)(r.qk.y&0xffff)), kHi=b2f((u16)(r.qk.y>>16));
    float vi =b2f(r.v);
    Sx = Sx*r.d.x + sap*bLo + vi*kLo;
    Sy = Sy*r.d.y + sap*bHi + vi*kHi;
    return Sx*b2f((u16)(r.qk.x&0xffff)) + Sy*b2f((u16)(r.qk.x>>16));
  };

  SR A0=ld(0), A1=ld(1), A2=ld(2), A3=ld(3), A4=ld(4), A5=ld(5), A6=ld(6), A7=ld(7);
  for (int g=0; g<120; ++g){
    int tn = g*8 + 8;
    float yp[8];
#define STEPR(AR, S_) { yp[S_] = dostep(AR); int t_ = tn + (S_); \
    AR = ld(t_ < TDIM ? t_ : TDIM-1); }
    STEPR(A0,0) STEPR(A1,1) __builtin_amdgcn_sched_barrier(0);
    STEPR(A2,2) STEPR(A3,3) __builtin_amdgcn_sched_barrier(0);
    STEPR(A4,4) STEPR(A5,5) __builtin_amdgcn_sched_barrier(0);
    STEPR(A6,6) STEPR(A7,7) __builtin_amdgcn_sched_barrier(0);
#undef STEPR
    // deferred y reductions: 8 independent butterflies, 8 lanes store
    #pragma unroll
    for (int s=0; s<8; ++s){
      yp[s] = row_red16(yp[s]);
      yp[s] += xor16(yp[s]);
    }
    if (jg < 8){
      float out = 0.f;
      #pragma unroll
      for (int s=0; s<8; ++s) if (jg==s) out = yp[s];   // static idx (no scratch)
      yb[(size_t)b*TDIM*CDIM + (size_t)(g*8+jg)*CDIM + h*NDIM + row] = out;
    }
  }
}

// ---------------------------------------------------------------------------
// 7) GroupNorm + bonus term + *g  -> bf16 YG (input of the final GEMM)
// r and k come interleaved from QKI; v from the relocated VS plane.
__global__ __launch_bounds__(256) void final_kernel(
  const float* yb, const uint4* qki, const u16* vs,
  const float* rk, const float* lnw, const float* lnb, const u16* gl, u16* yg)
{
  int row = blockIdx.x, tid = threadIdx.x;
  int c = tid*8;
  size_t base = (size_t)row*CDIM + c;
  float y[8], rf[8], kf[8], vf[8], rkf[8], lw[8], lb[8], gf[8];
  ld8f(yb+base, y);
  const uint4* qke = (const uint4*)((const char*)qki + (size_t)row*8192 + (size_t)c*4);
  uint4 e0 = qke[0], e1 = qke[1];
  rf[0]=b2f((u16)(e0.x&0xffff)); rf[1]=b2f((u16)(e0.x>>16));
  rf[2]=b2f((u16)(e0.z&0xffff)); rf[3]=b2f((u16)(e0.z>>16));
  rf[4]=b2f((u16)(e1.x&0xffff)); rf[5]=b2f((u16)(e1.x>>16));
  rf[6]=b2f((u16)(e1.z&0xffff)); rf[7]=b2f((u16)(e1.z>>16));
  kf[0]=b2f((u16)(e0.y&0xffff)); kf[1]=b2f((u16)(e0.y>>16));
  kf[2]=b2f((u16)(e0.w&0xffff)); kf[3]=b2f((u16)(e0.w>>16));
  kf[4]=b2f((u16)(e1.y&0xffff)); kf[5]=b2f((u16)(e1.y>>16));
  kf[6]=b2f((u16)(e1.w&0xffff)); kf[7]=b2f((u16)(e1.w>>16));
  unpack8(*(const uint4*)(vs+base), vf);
  ld8f(rk+c,  rkf);   // r_k is [H*N]=[C] flat
  ld8f(lnw+c, lw);
  ld8f(lnb+c, lb);
  unpack8(*(const uint4*)(gl+base), gf);
  float sy=0.f, syy=0.f, coef=0.f;
  #pragma unroll
  for (int j=0;j<8;j++){ sy+=y[j]; syy+=y[j]*y[j]; coef += rf[j]*kf[j]*rkf[j]; }
  sy  += __shfl_xor(sy,1);  sy  += __shfl_xor(sy,2);  sy  += __shfl_xor(sy,4);
  syy += __shfl_xor(syy,1); syy += __shfl_xor(syy,2); syy += __shfl_xor(syy,4);
  coef+= __shfl_xor(coef,1);coef+= __shfl_xor(coef,2);coef+= __shfl_xor(coef,4);
  float mu  = sy*(1.f/64.f);
  float var = syy*(1.f/64.f) - mu*mu;
  float rs  = rsqrtf(var + 6.4e-4f);    // EPS_GN = 1e-5*64
  float o[8];
  #pragma unroll
  for (int j=0;j<8;j++)
    o[j] = (((y[j]-mu)*rs)*lw[j] + lb[j] + coef*vf[j]) * gf[j];
  *(uint4*)(yg+base) = pack8(o);
}

// ---------------------------------------------------------------------------
extern "C" void kernel_launch(void* const* d_in, const int* in_sizes, int n_in,
                              void* d_out, int out_size, void* d_ws, size_t ws_size,
                              hipStream_t stream)
{
  const float* x      = (const float*)d_in[0];
  const float* vfirst = (const float*)d_in[1];
  const float* c_r = (const float*)d_in[2];
  const float* c_w = (const float*)d_in[3];
  const float* c_k = (const float*)d_in[4];
  const float* c_v = (const float*)d_in[5];
  const float* c_a = (const float*)d_in[6];
  const float* c_g = (const float*)d_in[7];
  const float* w0i = (const float*)d_in[8];
  const float* w1i = (const float*)d_in[9];
  const float* w2i = (const float*)d_in[10];
  const float* a0i = (const float*)d_in[11];
  const float* a1i = (const float*)d_in[12];
  const float* a2i = (const float*)d_in[13];
  const float* v0i = (const float*)d_in[14];
  const float* v1i = (const float*)d_in[15];
  const float* v2i = (const float*)d_in[16];
  const float* g1i = (const float*)d_in[17];
  const float* g2i = (const float*)d_in[18];
  const float* kki = (const float*)d_in[19];
  const float* kai = (const float*)d_in[20];
  const float* rki = (const float*)d_in[21];
  const float* Wr  = (const float*)d_in[22];
  const float* Wk  = (const float*)d_in[23];
  const float* Wv  = (const float*)d_in[24];
  const float* Wo  = (const float*)d_in[25];
  const float* lnw = (const float*)d_in[26];
  const float* lnb = (const float*)d_in[27];

  char* ws = (char*)d_ws;
  const size_t S2 = (size_t)BT*CDIM*2;    // bf16 [BT,C] plane = 15,728,640 B
  // bf16 mix planes [0, 6*S2)  (later aliased by scan inputs)
  u16* MIXR = (u16*)(ws + 0*S2);
  u16* MIXW = (u16*)(ws + 1*S2);
  u16* MIXK = (u16*)(ws + 2*S2);
  u16* MIXV = (u16*)(ws + 3*S2);
  u16* MIXA = (u16*)(ws + 4*S2);
  u16* MIXG = (u16*)(ws + 5*S2);
  // bf16 projection outputs
  u16* RBUF = (u16*)(ws + 6*S2);
  u16* KBUF = (u16*)(ws + 7*S2);
  u16* VRAW = (u16*)(ws + 8*S2);
  // single reusable bf16 weight slot (Wr -> Wk -> Wv -> Wo, stream-ordered)
  char* WB = ws + 9*S2;
  u16* WSLOT = (u16*)WB;            // 2048*2048*2 = 8,388,608 B
  char* WT = WB + 8388608;
  u16* W1T = (u16*)(WT + 0);        // [128,2048]
  u16* A1T = (u16*)(WT + 524288);
  u16* V1T = (u16*)(WT + 1048576);
  u16* G1T = (u16*)(WT + 1572864);  // [256,2048]
  u16* W2T = (u16*)(WT + 2621440);  // [2048,128]
  u16* A2T = (u16*)(WT + 3145728);
  u16* V2T = (u16*)(WT + 3670016);
  u16* G2T = (u16*)(WT + 4194304);  // [2048,256]
  char* HB = WT + 5242880;
  u16* HW = (u16*)(HB + 0);         // [BT,128]
  u16* HA = (u16*)(HB + 983040);
  u16* HV = (u16*)(HB + 1966080);
  u16* HG = (u16*)(HB + 2949120);   // [BT,256]
  char* L2 = HB + 4915200;
  u16* WL = (u16*)(L2 + 0*S2);
  u16* AL = (u16*)(L2 + 1*S2);
  u16* VL = (u16*)(L2 + 2*S2);
  u16* GL = (u16*)(L2 + 3*S2);      // ws end = L2 + 4*S2 = 223,019,008 B (~212.7 MiB)
  // aliases (producers strictly after last consumer of the dead buffers):
  float* WDEC = (float*)(ws + 0*S2);    // fp32 decay over MIXR+MIXW
  uint4* QKI  = (uint4*)(ws + 2*S2);    // interleaved q/k pairs over MIXK+MIXV
  uint4* ABI  = (uint4*)(ws + 4*S2);    // interleaved a/b pairs over MIXA+MIXG
  u16*   VS6  = (u16*)(ws + 6*S2);      // v bf16 over RBUF (post: in-thread r/w)
  float* YBUF = (float*)(L2 + 0*S2);    // fp32 over WL+AL
  u16* YG = (u16*)(L2 + 2*S2);          // over VL
  (void)in_sizes; (void)n_in; (void)out_size; (void)ws_size;

  // 1) transpose+pad+cvt LoRA weights
  TJobs8 tj;
  tj.j[0] = (TJob){w1i, W1T, 2048,  96, 128, 2048};
  tj.j[1] = (TJob){a1i, A1T, 2048,  96, 128, 2048};
  tj.j[2] = (TJob){v1i, V1T, 2048,  64, 128, 2048};
  tj.j[3] = (TJob){g1i, G1T, 2048, 256, 256, 2048};
  tj.j[4] = (TJob){w2i, W2T,   96, 2048, 2048, 128};
  tj.j[5] = (TJob){a2i, A2T,   96, 2048, 2048, 128};
  tj.j[6] = (TJob){v2i, V2T,   64, 2048, 2048, 128};
  tj.j[7] = (TJob){g2i, G2T,  256, 2048, 2048, 256};
  transpose_pad_kernel<<<dim3(2048,1,8), 256, 0, stream>>>(tj);

  // 2) token-shift mixes (fp32 in, bf16 out)
  mix_kernel<<<dim3(BT*CDIM/8/256), 256, 0, stream>>>(
      x, c_r, c_w, c_k, c_v, c_a, c_g, MIXR, MIXW, MIXK, MIXV, MIXA, MIXG);

  // 3) big projections r,k,v (bf16 C), weight slot reused via stream ordering
  {
    GemmJobs gj;
    cvt_kernel<<<dim3(2048), 256, 0, stream>>>(Wr, WSLOT);
    gj.j[0] = (GemmJob){MIXR, WSLOT, RBUF, 30, 16, 2048, 2048, 2048, 2048};
    gj.j[1] = gj.j[0]; gj.j[2] = gj.j[0]; gj.j[3] = gj.j[0];
    gemm_bt_kernel<u16><<<dim3(480,1,1), 256, 0, stream>>>(gj);
    cvt_kernel<<<dim3(2048), 256, 0, stream>>>(Wk, WSLOT);
    gj.j[0] = (GemmJob){MIXK, WSLOT, KBUF, 30, 16, 2048, 2048, 2048, 2048};
    gemm_bt_kernel<u16><<<dim3(480,1,1), 256, 0, stream>>>(gj);
    cvt_kernel<<<dim3(2048), 256, 0, stream>>>(Wv, WSLOT);
    gj.j[0] = (GemmJob){MIXV, WSLOT, VRAW, 30, 16, 2048, 2048, 2048, 2048};
    gemm_bt_kernel<u16><<<dim3(480,1,1), 256, 0, stream>>>(gj);
  }

  // 4) LoRA first halves (bf16 C)
  GemmJobs lj1;
  lj1.j[0] = (GemmJob){MIXW, W1T, HW, 30, 1, 2048, 2048, 2048, 128};
  lj1.j[1] = (GemmJob){MIXA, A1T, HA, 30, 1, 2048, 2048, 2048, 128};
  lj1.j[2] = (GemmJob){MIXV, V1T, HV, 30, 1, 2048, 2048, 2048, 128};
  lj1.j[3] = (GemmJob){MIXG, G1T, HG, 30, 2, 2048, 2048, 2048, 256};
  gemm_bt_kernel<u16><<<dim3(60,1,4), 256, 0, stream>>>(lj1);

  // 5) mid activations
  act_kernel<<<dim3(3840,1,2), 256, 0, stream>>>(HW, HG);

  // 6) LoRA second halves (bf16 C)
  GemmJobs lj2;
  lj2.j[0] = (GemmJob){HW, W2T, WL, 30, 16, 128, 128, 128, 2048};
  lj2.j[1] = (GemmJob){HA, A2T, AL, 30, 16, 128, 128, 128, 2048};
  lj2.j[2] = (GemmJob){HV, V2T, VL, 30, 16, 128, 128, 128, 2048};
  lj2.j[3] = (GemmJob){HG, G2T, GL, 30, 16, 256, 256, 256, 2048};
  gemm_bt_kernel<u16><<<dim3(480,1,4), 256, 0, stream>>>(lj2);

  // 7) post elementwise -> scan inputs (write into dead mix planes)
  post_kernel<<<dim3(BT), 256, 0, stream>>>(
      RBUF, KBUF, VRAW, vfirst, WL, AL, VL, w0i, a0i, v0i, kki, kai,
      WDEC, QKI, ABI, VS6);

  // 8) recurrence (8 blocks/head, 8-row octants, 4 waves/SIMD, depth-8 pipe)
  scan_kernel<<<dim3(1024), 256, 0, stream>>>(
      WDEC, (const uint2*)QKI, (const uint2*)ABI, VS6, YBUF);

  // 9) GroupNorm + bonus + *g -> bf16 YG
  final_kernel<<<dim3(BT), 256, 0, stream>>>(
      YBUF, QKI, VS6, rki, lnw, lnb, GL, YG);

  // 10) output projection (fp32 C = d_out)
  cvt_kernel<<<dim3(2048), 256, 0, stream>>>(Wo, WSLOT);
  GemmJobs oj;
  oj.j[0] = (GemmJob){YG, WSLOT, d_out, 30, 16, 2048, 2048, 2048, 2048};
  oj.j[1] = oj.j[0]; oj.j[2] = oj.j[0]; oj.j[3] = oj.j[0];
  gemm_bt_kernel<float><<<dim3(480,1,1), 256, 0, stream>>>(oj);
}

// Round 6
// 901.835 us; speedup vs baseline: 1.0943x; 1.0943x over previous
//
#include <hip/hip_runtime.h>
#include <stdint.h>

// Problem constants (B,T,C,H,N) = (4,960,2048,32,64)
#define BDIM 4
#define TDIM 960
#define CDIM 2048
#define HDIM 32
#define NDIM 64
#define BT   (BDIM*TDIM)   // 3840 rows

typedef unsigned short u16;
typedef __attribute__((ext_vector_type(8))) short short8;   // 8 bf16 (4 VGPRs)
typedef __attribute__((ext_vector_type(4))) float f32x4;
typedef __attribute__((ext_vector_type(2))) float f32x2;

__device__ __forceinline__ float b2f(u16 u){
  union{unsigned int i; float f;}x; x.i=((unsigned int)u)<<16; return x.f;
}
__device__ __forceinline__ u16 f2b(float f){
  union{float f; unsigned int i;}x; x.f=f;
  unsigned int r = x.i + 0x7fffu + ((x.i>>16)&1u);   // RNE
  return (u16)(r>>16);
}
__device__ __forceinline__ unsigned pk2(float lo, float hi){
  return (unsigned)f2b(lo) | ((unsigned)f2b(hi)<<16);
}
__device__ __forceinline__ void unpack8(uint4 p, float* o){
  o[0]=b2f((u16)(p.x&0xffff)); o[1]=b2f((u16)(p.x>>16));
  o[2]=b2f((u16)(p.y&0xffff)); o[3]=b2f((u16)(p.y>>16));
  o[4]=b2f((u16)(p.z&0xffff)); o[5]=b2f((u16)(p.z>>16));
  o[6]=b2f((u16)(p.w&0xffff)); o[7]=b2f((u16)(p.w>>16));
}
__device__ __forceinline__ uint4 pack8(const float* o){
  uint4 p;
  p.x = pk2(o[0],o[1]);
  p.y = pk2(o[2],o[3]);
  p.z = pk2(o[4],o[5]);
  p.w = pk2(o[6],o[7]);
  return p;
}
__device__ __forceinline__ void ld8f(const float* p, float* o){
  float4 a = *(const float4*)p;
  float4 b = *(const float4*)(p+4);
  o[0]=a.x;o[1]=a.y;o[2]=a.z;o[3]=a.w;o[4]=b.x;o[5]=b.y;o[6]=b.z;o[7]=b.w;
}
__device__ __forceinline__ float sigm(float x){ return 1.f/(1.f+expf(-x)); }
__device__ __forceinline__ void stc(float* p, float v){ *p = v; }
__device__ __forceinline__ void stc(u16* p, float v){ *p = f2b(v); }
__device__ __forceinline__ f32x2 lo2(f32x4 v){ return __builtin_shufflevector(v, v, 0, 1); }
__device__ __forceinline__ f32x2 hi2(f32x4 v){ return __builtin_shufflevector(v, v, 2, 3); }

// 16-lane butterfly sum on the VALU pipe (DPP), zero LDS traffic.
__device__ __forceinline__ float row_red16(float x){
  x += __int_as_float(__builtin_amdgcn_update_dpp(0, __float_as_int(x), 0xB1,  0xF, 0xF, true));
  x += __int_as_float(__builtin_amdgcn_update_dpp(0, __float_as_int(x), 0x4E,  0xF, 0xF, true));
  x += __int_as_float(__builtin_amdgcn_update_dpp(0, __float_as_int(x), 0x141, 0xF, 0xF, true));
  x += __int_as_float(__builtin_amdgcn_update_dpp(0, __float_as_int(x), 0x140, 0xF, 0xF, true));
  return x;
}

// ---------------------------------------------------------------------------
// 0) fp32 -> bf16 weight conversion (one 2048x2048 matrix per launch)
__global__ __launch_bounds__(256) void cvt_kernel(const float* src, u16* dst){
  size_t i = ((size_t)blockIdx.x*256 + threadIdx.x)*8;
  float v[8]; ld8f(src+i, v);
  *(uint4*)(dst+i) = pack8(v);
}

// ---------------------------------------------------------------------------
// 1) batched transpose+pad+cvt for LoRA weights (tiny: <6 MB total)
struct TJob { const float* src; u16* dst; int R, Cs, DR, DC; };
struct TJobs8 { TJob j[8]; };

__global__ __launch_bounds__(256) void transpose_pad_kernel(TJobs8 jobs){
  TJob jb = jobs.j[blockIdx.z];
  int idx = blockIdx.x*256 + threadIdx.x;
  int total = jb.DR*jb.DC;
  if (idx >= total) return;
  int i = idx / jb.DC, k = idx % jb.DC;
  float v = 0.f;
  if (i < jb.Cs && k < jb.R) v = jb.src[(size_t)k*jb.Cs + i];
  jb.dst[idx] = f2b(v);
}

// ---------------------------------------------------------------------------
// 2) token-shift mixes: m = x + (x_prev - x)*coef  (6 bf16 outputs)
__global__ __launch_bounds__(256) void mix_kernel(
  const float* x,
  const float* cr, const float* cw, const float* ck,
  const float* cv, const float* ca, const float* cg,
  u16* mr, u16* mw, u16* mk, u16* mv, u16* ma, u16* mg)
{
  size_t tid = (size_t)blockIdx.x*256 + threadIdx.x;
  size_t base = tid*8;
  int c = (int)(base % CDIM);
  int row = (int)(base / CDIM);
  int t = row % TDIM;
  float xc[8], xp[8], xx[8], cf[8], o[8];
  ld8f(x+base, xc);
  if (t > 0) {
    ld8f(x+base-CDIM, xp);
  } else {
    for(int j=0;j<8;j++) xp[j]=0.f;
  }
  #pragma unroll
  for(int j=0;j<8;j++) xx[j]=xp[j]-xc[j];
#define DOMIX(CP, OP) do { ld8f(CP+c, cf); \
  _Pragma("unroll") for(int j=0;j<8;j++) o[j]=xc[j]+xx[j]*cf[j]; \
  *(uint4*)(OP+base)=pack8(o); } while(0)
  DOMIX(cr, mr); DOMIX(cw, mw); DOMIX(ck, mk);
  DOMIX(cv, mv); DOMIX(ca, ma); DOMIX(cg, mg);
#undef DOMIX
}

// ---------------------------------------------------------------------------
// 3) bf16 GEMM, C[M,N] = A[M,K] * Bt[N,K]^T  (B^T layout, m97 structure)
struct GemmJob {
  const u16* A; const u16* Bt; void* C;
  int nbm, nbn, K, lda, ldb, ldc;
};
struct GemmJobs { GemmJob j[4]; };

template<typename TC>
__global__ __launch_bounds__(256, 2) void gemm_bt_kernel(GemmJobs jobs){
  GemmJob jb = jobs.j[blockIdx.z];
  int bm = blockIdx.x % jb.nbm;
  int bn = blockIdx.x / jb.nbm;
  if (bn >= jb.nbn) return;
  __shared__ __attribute__((aligned(16))) u16 As[128*64];
  __shared__ __attribute__((aligned(16))) u16 Bs[128*64];
  int tid = threadIdx.x;
  int wave = tid>>6, lane = tid&63;
  int wr = wave>>1, wc = wave&1;
  f32x4 acc[4][4];
  #pragma unroll
  for(int i=0;i<4;i++)
    #pragma unroll
    for(int j=0;j<4;j++) acc[i][j] = (f32x4){0.f,0.f,0.f,0.f};
  const int rA0 = bm*128;
  const int rB0 = bn*128;
  int srow = (lane>>3);        // 0..7 row within 8-row slab
  int scol = (lane&7)*8;       // k element offset (8 bf16 = 16B)
  for (int k0=0; k0<jb.K; k0+=64){
    #pragma unroll
    for (int it=0; it<4; ++it){
      int rr = wave*32 + it*8;  // wave-uniform
      const u16* gA = jb.A + (size_t)(rA0 + rr + srow)*jb.lda + (k0 + scol);
      __builtin_amdgcn_global_load_lds((const __attribute__((address_space(1))) void*)gA,
          (__attribute__((address_space(3))) void*)&As[rr*64], 16, 0, 0);
      const u16* gB = jb.Bt + (size_t)(rB0 + rr + srow)*jb.ldb + (k0 + scol);
      __builtin_amdgcn_global_load_lds((const __attribute__((address_space(1))) void*)gB,
          (__attribute__((address_space(3))) void*)&Bs[rr*64], 16, 0, 0);
    }
    __syncthreads();   // compiler emits vmcnt(0) drain before s_barrier
    #pragma unroll
    for (int kc=0; kc<2; ++kc){
      short8 af[4], bfr[4];
      int ko = kc*32 + (lane>>4)*8;
      #pragma unroll
      for (int mi=0; mi<4; ++mi)
        af[mi] = *(const short8*)&As[(wr*64 + mi*16 + (lane&15))*64 + ko];
      #pragma unroll
      for (int ni=0; ni<4; ++ni)
        bfr[ni] = *(const short8*)&Bs[(wc*64 + ni*16 + (lane&15))*64 + ko];
      #pragma unroll
      for (int mi=0; mi<4; ++mi)
        #pragma unroll
        for (int ni=0; ni<4; ++ni)
          acc[mi][ni] = __builtin_amdgcn_mfma_f32_16x16x32_bf16(af[mi], bfr[ni], acc[mi][ni], 0, 0, 0);
    }
    __syncthreads();
  }
  // epilogue: C/D layout col=lane&15, row=(lane>>4)*4+reg  [m89/m91 verified]
  TC* C = (TC*)jb.C;
  int cn = (lane&15);
  int rq = (lane>>4)*4;
  #pragma unroll
  for (int mi=0; mi<4; ++mi){
    #pragma unroll
    for (int ni=0; ni<4; ++ni){
      int col = rB0 + wc*64 + ni*16 + cn;
      int row = rA0 + wr*64 + mi*16 + rq;
      #pragma unroll
      for (int e=0; e<4; ++e)
        stc(&C[(size_t)(row+e)*jb.ldc + col], acc[mi][ni][e]);
    }
  }
}

// ---------------------------------------------------------------------------
// 4) mid-LoRA activations: tanh on hw, sigmoid on hg (pads stay 0 -> tanh(0)=0)
__global__ __launch_bounds__(256) void act_kernel(u16* hw, u16* hg){
  int idx = blockIdx.x*256 + threadIdx.x;
  if (blockIdx.z==0){ if (idx < BT*128) hw[idx] = f2b(tanhf(b2f(hw[idx]))); }
  else              { if (idx < BT*256) hg[idx] = f2b(sigm(b2f(hg[idx]))); }
}

// ---------------------------------------------------------------------------
// 5) post-GEMM elementwise -> scan inputs, now mostly FP32 so the scan loop
// has no bf16 converts on d/a/b/k:
//   DEC fp32 [BT,2048]          (over MIXR+MIXW)
//   AF  fp32 [BT,2048]          (over MIXK+MIXV)   a = -kk_normalized
//   BF  fp32 [BT,2048]          (over MIXA+MIXG)   b = kk_normalized * av
//   KF  fp32 split: lo cols 0-1023 over KBUF, hi cols 1024-2047 over VRAW
//       (row-local in-place rewrite; __syncthreads between read and write)
//   VS  bf16 [BT,2048]          (over dead WSLOT/WT/HB region)
//   COEF fp32 [BT,32]           per-(row,head) bonus coef  Σ r*kfin*r_k
// q stays bf16 in RBUF (read directly by the scan).
__global__ __launch_bounds__(256) void post_kernel(
  const u16* rbuf, const u16* kbuf, const u16* vraw, const float* vfirst,
  const u16* wl, const u16* al, const u16* vl,
  const float* w0, const float* a0, const float* v0,
  const float* kkc, const float* kac, const float* rki,
  float* dout, float* af, float* bf, float* kflo, float* kfhi,
  u16* vs, float* coefp)
{
  int row = blockIdx.x, tid = threadIdx.x;
  int c = tid*8;
  size_t base = (size_t)row*CDIM + c;
  float qf[8], kf[8], vr[8], vf[8], wlf[8], alf[8], vlf[8], w0f[8], a0f[8], v0f[8], kkf[8], kaf[8], rkf[8];
  unpack8(*(const uint4*)(rbuf+base), qf);
  unpack8(*(const uint4*)(kbuf+base), kf);
  unpack8(*(const uint4*)(vraw+base), vr);
  ld8f(vfirst+base, vf);
  unpack8(*(const uint4*)(wl+base), wlf);
  unpack8(*(const uint4*)(al+base), alf);
  unpack8(*(const uint4*)(vl+base), vlf);
  ld8f(w0+c, w0f);
  ld8f(a0+c, a0f);
  ld8f(v0+c, v0f);
  ld8f(kkc+c, kkf);
  ld8f(kac+c, kaf);
  ld8f(rki+c, rkf);
  float dv[8], av[8], vv[8], kkr[8], kfin[8], asv[8], bsv[8];
  float ssq = 0.f;
  #pragma unroll
  for (int j=0;j<8;j++){
    float wv = -log1pf(expf(-(w0f[j]+wlf[j]))) - 0.5f;       // -softplus(-z)-0.5
    dv[j]  = expf(-expf(wv));                                // decay
    av[j]  = sigm(a0f[j]+alf[j]);
    vv[j]  = vr[j] + (vf[j]-vr[j])*sigm(v0f[j]+vlf[j]);
    kkr[j] = kf[j]*kkf[j];
    ssq   += kkr[j]*kkr[j];
    kfin[j]= kf[j]*(1.f + (av[j]-1.f)*kaf[j]);
  }
  // head = 8 consecutive lanes (thread covers 8 contiguous c, head = 64 c)
  ssq += __shfl_xor(ssq,1); ssq += __shfl_xor(ssq,2); ssq += __shfl_xor(ssq,4);
  float inv = 1.f/fmaxf(sqrtf(ssq), 1e-12f);
  float coef = 0.f;
  #pragma unroll
  for (int j=0;j<8;j++){
    float kkn = kkr[j]*inv; asv[j] = -kkn; bsv[j] = kkn*av[j];
    coef += qf[j]*kfin[j]*rkf[j];
  }
  coef += __shfl_xor(coef,1); coef += __shfl_xor(coef,2); coef += __shfl_xor(coef,4);
  // KF writes alias KBUF/VRAW (other threads' read regions) -> barrier first
  __syncthreads();
  *(float4*)(dout+base)   = make_float4(dv[0],dv[1],dv[2],dv[3]);
  *(float4*)(dout+base+4) = make_float4(dv[4],dv[5],dv[6],dv[7]);
  float* afp = af + base;
  *(float4*)(afp)   = make_float4(asv[0],asv[1],asv[2],asv[3]);
  *(float4*)(afp+4) = make_float4(asv[4],asv[5],asv[6],asv[7]);
  float* bfp = bf + base;
  *(float4*)(bfp)   = make_float4(bsv[0],bsv[1],bsv[2],bsv[3]);
  *(float4*)(bfp+4) = make_float4(bsv[4],bsv[5],bsv[6],bsv[7]);
  float* kfp = (c < 1024) ? (kflo + (size_t)row*1024 + c)
                          : (kfhi + (size_t)row*1024 + (c-1024));
  *(float4*)(kfp)   = make_float4(kfin[0],kfin[1],kfin[2],kfin[3]);
  *(float4*)(kfp+4) = make_float4(kfin[4],kfin[5],kfin[6],kfin[7]);
  *(uint4*)(vs+base) = pack8(vv);
  if ((tid&7)==0) coefp[(size_t)row*32 + (tid>>3)] = coef;
}

// ---------------------------------------------------------------------------
// 6) the linear recurrence. Rows of S evolve independently:
//    S_t[i,:] = S_{t-1}[i,:]*(diag(d)+a b^T) + v_i k^T
// Round-6: keep the PROVEN round-4 structure (512 blocks, 4/head, 16-lane col
// groups, 4 cols/thread, pure-DPP reduction, depth-8 named-record pipeline,
// sched_barrier fences, launch_bounds(256,2) for VGPR headroom — round 5
// proved tight caps collapse the pipeline). Changes: d/a/b/k streams are now
// FP32 (no converts in the loop; only q,v remain bf16 = 5 shifts/step vs 17)
// and the math is written on float2 vectors so the backend can emit
// v_pk_fma_f32 (packed fp32 = the 157TF rate). 6 VMEM/step, 19-VGPR records.
__global__ __launch_bounds__(256, 2) void scan_kernel(
  const float* __restrict__ decayp, const u16* __restrict__ qb,
  const float* __restrict__ kflo, const float* __restrict__ kfhi,
  const float* __restrict__ af, const float* __restrict__ bf,
  const u16* __restrict__ vs, float* __restrict__ yb)
{
  int blk = blockIdx.x;          // b*128 + h*4 + qtr
  int b    = blk >> 7;
  int h    = (blk >> 2) & 31;
  int qtr  = blk & 3;
  int tid  = threadIdx.x;
  int jg   = tid & 15;           // col group (4 cols)
  int ii   = tid >> 4;           // row within quarter (0..15)
  int row  = qtr*16 + ii;

  size_t co4 = (size_t)(h*256 + jg*16);   // fp32 full-width col byte offset
  const char* dP = (const char*)decayp + (size_t)b*TDIM*8192 + co4;
  const char* aP = (const char*)af     + (size_t)b*TDIM*8192 + co4;
  const char* bP = (const char*)bf     + (size_t)b*TDIM*8192 + co4;
  const char* kP = (h < 16)
      ? ((const char*)kflo + (size_t)b*TDIM*4096 + (size_t)(h*256 + jg*16))
      : ((const char*)kfhi + (size_t)b*TDIM*4096 + (size_t)((h-16)*256 + jg*16));
  const char* qP = (const char*)qb + (size_t)b*TDIM*4096 + (size_t)(h*128 + jg*8);
  const char* vP = (const char*)vs + (size_t)b*TDIM*4096 + (size_t)(h*128 + row*2);

  f32x2 Sa = (f32x2){0.f,0.f}, Sb = (f32x2){0.f,0.f};

  struct SR { f32x4 d, k, a, b; uint2 q; u16 v; };   // 19 VGPRs
  auto ld = [&](int t)->SR{
    SR r;
    size_t o8 = (size_t)t*8192, o4 = (size_t)t*4096;
    r.d = *(const f32x4*)(dP + o8);
    r.a = *(const f32x4*)(aP + o8);
    r.b = *(const f32x4*)(bP + o8);
    r.k = *(const f32x4*)(kP + o4);
    r.q = *(const uint2*)(qP + o4);
    r.v = *(const u16*)(vP + o4);
    return r;
  };
  auto dostep = [&](const SR& r)->float{
    f32x2 t = Sa*lo2(r.a) + Sb*hi2(r.a);       // pk mul + pk fma
    float sap = t[0] + t[1];
    sap = row_red16(sap);                      // pure-VALU butterfly
    float vi = b2f(r.v);
    f32x2 s2 = (f32x2){sap,sap};
    f32x2 v2 = (f32x2){vi,vi};
    Sa = Sa*lo2(r.d) + s2*lo2(r.b) + v2*lo2(r.k);
    Sb = Sb*hi2(r.d) + s2*hi2(r.b) + v2*hi2(r.k);
    f32x2 q01 = (f32x2){b2f((u16)(r.q.x&0xffff)), b2f((u16)(r.q.x>>16))};
    f32x2 q23 = (f32x2){b2f((u16)(r.q.y&0xffff)), b2f((u16)(r.q.y>>16))};
    f32x2 u = Sa*q01 + Sb*q23;
    return u[0] + u[1];
  };

  SR A0=ld(0), A1=ld(1), A2=ld(2), A3=ld(3), A4=ld(4), A5=ld(5), A6=ld(6), A7=ld(7);
  for (int g=0; g<120; ++g){
    int tn = g*8 + 8;
    float yp[8];
#define STEPR(AR, S_) { yp[S_] = dostep(AR); int t_ = tn + (S_); \
    AR = ld(t_ < TDIM ? t_ : TDIM-1); }
    STEPR(A0,0) STEPR(A1,1) __builtin_amdgcn_sched_barrier(0);
    STEPR(A2,2) STEPR(A3,3) __builtin_amdgcn_sched_barrier(0);
    STEPR(A4,4) STEPR(A5,5) __builtin_amdgcn_sched_barrier(0);
    STEPR(A6,6) STEPR(A7,7) __builtin_amdgcn_sched_barrier(0);
#undef STEPR
    // deferred y reductions: 8 independent DPP butterflies, 8 lanes store
    #pragma unroll
    for (int s=0; s<8; ++s) yp[s] = row_red16(yp[s]);
    if (jg < 8){
      float out = 0.f;
      #pragma unroll
      for (int s=0; s<8; ++s) if (jg==s) out = yp[s];   // static idx (no scratch)
      yb[(size_t)b*TDIM*CDIM + (size_t)(g*8+jg)*CDIM + h*NDIM + row] = out;
    }
  }
}

// ---------------------------------------------------------------------------
// 7) GroupNorm + bonus term + *g  -> bf16 YG (input of the final GEMM)
// coef precomputed per (row,head) in post; v from VS plane.
__global__ __launch_bounds__(256) void final_kernel(
  const float* yb, const u16* vs, const float* coefp,
  const float* lnw, const float* lnb, const u16* gl, u16* yg)
{
  int row = blockIdx.x, tid = threadIdx.x;
  int c = tid*8;
  size_t base = (size_t)row*CDIM + c;
  float y[8], vf[8], lw[8], lb[8], gf[8];
  ld8f(yb+base, y);
  unpack8(*(const uint4*)(vs+base), vf);
  ld8f(lnw+c, lw);
  ld8f(lnb+c, lb);
  unpack8(*(const uint4*)(gl+base), gf);
  float coef = coefp[(size_t)row*32 + (tid>>3)];
  float sy=0.f, syy=0.f;
  #pragma unroll
  for (int j=0;j<8;j++){ sy+=y[j]; syy+=y[j]*y[j]; }
  sy  += __shfl_xor(sy,1);  sy  += __shfl_xor(sy,2);  sy  += __shfl_xor(sy,4);
  syy += __shfl_xor(syy,1); syy += __shfl_xor(syy,2); syy += __shfl_xor(syy,4);
  float mu  = sy*(1.f/64.f);
  float var = syy*(1.f/64.f) - mu*mu;
  float rs  = rsqrtf(var + 6.4e-4f);    // EPS_GN = 1e-5*64
  float o[8];
  #pragma unroll
  for (int j=0;j<8;j++)
    o[j] = (((y[j]-mu)*rs)*lw[j] + lb[j] + coef*vf[j]) * gf[j];
  *(uint4*)(yg+base) = pack8(o);
}

// ---------------------------------------------------------------------------
extern "C" void kernel_launch(void* const* d_in, const int* in_sizes, int n_in,
                              void* d_out, int out_size, void* d_ws, size_t ws_size,
                              hipStream_t stream)
{
  const float* x      = (const float*)d_in[0];
  const float* vfirst = (const float*)d_in[1];
  const float* c_r = (const float*)d_in[2];
  const float* c_w = (const float*)d_in[3];
  const float* c_k = (const float*)d_in[4];
  const float* c_v = (const float*)d_in[5];
  const float* c_a = (const float*)d_in[6];
  const float* c_g = (const float*)d_in[7];
  const float* w0i = (const float*)d_in[8];
  const float* w1i = (const float*)d_in[9];
  const float* w2i = (const float*)d_in[10];
  const float* a0i = (const float*)d_in[11];
  const float* a1i = (const float*)d_in[12];
  const float* a2i = (const float*)d_in[13];
  const float* v0i = (const float*)d_in[14];
  const float* v1i = (const float*)d_in[15];
  const float* v2i = (const float*)d_in[16];
  const float* g1i = (const float*)d_in[17];
  const float* g2i = (const float*)d_in[18];
  const float* kki = (const float*)d_in[19];
  const float* kai = (const float*)d_in[20];
  const float* rki = (const float*)d_in[21];
  const float* Wr  = (const float*)d_in[22];
  const float* Wk  = (const float*)d_in[23];
  const float* Wv  = (const float*)d_in[24];
  const float* Wo  = (const float*)d_in[25];
  const float* lnw = (const float*)d_in[26];
  const float* lnb = (const float*)d_in[27];

  char* ws = (char*)d_ws;
  const size_t S2 = (size_t)BT*CDIM*2;    // bf16 [BT,C] plane = 15,728,640 B
  // bf16 mix planes [0, 6*S2)  (later aliased by scan inputs)
  u16* MIXR = (u16*)(ws + 0*S2);
  u16* MIXW = (u16*)(ws + 1*S2);
  u16* MIXK = (u16*)(ws + 2*S2);
  u16* MIXV = (u16*)(ws + 3*S2);
  u16* MIXA = (u16*)(ws + 4*S2);
  u16* MIXG = (u16*)(ws + 5*S2);
  // bf16 projection outputs
  u16* RBUF = (u16*)(ws + 6*S2);    // stays live: q stream for the scan
  u16* KBUF = (u16*)(ws + 7*S2);
  u16* VRAW = (u16*)(ws + 8*S2);
  // single reusable bf16 weight slot (Wr -> Wk -> Wv -> Wo, stream-ordered)
  char* WB = ws + 9*S2;
  u16* WSLOT = (u16*)WB;            // 2048*2048*2 = 8,388,608 B
  char* WT = WB + 8388608;
  u16* W1T = (u16*)(WT + 0);        // [128,2048]
  u16* A1T = (u16*)(WT + 524288);
  u16* V1T = (u16*)(WT + 1048576);
  u16* G1T = (u16*)(WT + 1572864);  // [256,2048]
  u16* W2T = (u16*)(WT + 2621440);  // [2048,128]
  u16* A2T = (u16*)(WT + 3145728);
  u16* V2T = (u16*)(WT + 3670016);
  u16* G2T = (u16*)(WT + 4194304);  // [2048,256]
  char* HB = WT + 5242880;
  u16* HW = (u16*)(HB + 0);         // [BT,128]
  u16* HA = (u16*)(HB + 983040);
  u16* HV = (u16*)(HB + 1966080);
  u16* HG = (u16*)(HB + 2949120);   // [BT,256]
  char* L2 = HB + 4915200;
  u16* WL = (u16*)(L2 + 0*S2);
  u16* AL = (u16*)(L2 + 1*S2);
  u16* VL = (u16*)(L2 + 2*S2);
  u16* GL = (u16*)(L2 + 3*S2);      // ws end = L2 + 4*S2 = 223,019,008 B (~212.7 MiB)
  // aliases (producers strictly after last consumer of the dead buffers):
  float* WDEC = (float*)(ws + 0*S2);    // fp32 decay over MIXR+MIXW
  float* AF   = (float*)(ws + 2*S2);    // fp32 a-stream over MIXK+MIXV
  float* BF   = (float*)(ws + 4*S2);    // fp32 b-stream over MIXA+MIXG
  float* KFLO = (float*)(ws + 7*S2);    // fp32 k cols 0-1023 over KBUF (row-local)
  float* KFHI = (float*)(ws + 8*S2);    // fp32 k cols 1024-2047 over VRAW
  u16*   VSW  = (u16*)(WB);             // v bf16 over WSLOT+WT+HB (dead; Wo cvt after final)
  float* COEF = (float*)(WB + 15728640);// [BT,32] fp32 bonus coefs
  float* YBUF = (float*)(L2 + 0*S2);    // fp32 over WL+AL
  u16* YG = (u16*)(L2 + 2*S2);          // over VL
  (void)in_sizes; (void)n_in; (void)out_size; (void)ws_size;

  // 1) transpose+pad+cvt LoRA weights
  TJobs8 tj;
  tj.j[0] = (TJob){w1i, W1T, 2048,  96, 128, 2048};
  tj.j[1] = (TJob){a1i, A1T, 2048,  96, 128, 2048};
  tj.j[2] = (TJob){v1i, V1T, 2048,  64, 128, 2048};
  tj.j[3] = (TJob){g1i, G1T, 2048, 256, 256, 2048};
  tj.j[4] = (TJob){w2i, W2T,   96, 2048, 2048, 128};
  tj.j[5] = (TJob){a2i, A2T,   96, 2048, 2048, 128};
  tj.j[6] = (TJob){v2i, V2T,   64, 2048, 2048, 128};
  tj.j[7] = (TJob){g2i, G2T,  256, 2048, 2048, 256};
  transpose_pad_kernel<<<dim3(2048,1,8), 256, 0, stream>>>(tj);

  // 2) token-shift mixes (fp32 in, bf16 out)
  mix_kernel<<<dim3(BT*CDIM/8/256), 256, 0, stream>>>(
      x, c_r, c_w, c_k, c_v, c_a, c_g, MIXR, MIXW, MIXK, MIXV, MIXA, MIXG);

  // 3) big projections r,k,v (bf16 C), weight slot reused via stream ordering
  {
    GemmJobs gj;
    cvt_kernel<<<dim3(2048), 256, 0, stream>>>(Wr, WSLOT);
    gj.j[0] = (GemmJob){MIXR, WSLOT, RBUF, 30, 16, 2048, 2048, 2048, 2048};
    gj.j[1] = gj.j[0]; gj.j[2] = gj.j[0]; gj.j[3] = gj.j[0];
    gemm_bt_kernel<u16><<<dim3(480,1,1), 256, 0, stream>>>(gj);
    cvt_kernel<<<dim3(2048), 256, 0, stream>>>(Wk, WSLOT);
    gj.j[0] = (GemmJob){MIXK, WSLOT, KBUF, 30, 16, 2048, 2048, 2048, 2048};
    gemm_bt_kernel<u16><<<dim3(480,1,1), 256, 0, stream>>>(gj);
    cvt_kernel<<<dim3(2048), 256, 0, stream>>>(Wv, WSLOT);
    gj.j[0] = (GemmJob){MIXV, WSLOT, VRAW, 30, 16, 2048, 2048, 2048, 2048};
    gemm_bt_kernel<u16><<<dim3(480,1,1), 256, 0, stream>>>(gj);
  }

  // 4) LoRA first halves (bf16 C)
  GemmJobs lj1;
  lj1.j[0] = (GemmJob){MIXW, W1T, HW, 30, 1, 2048, 2048, 2048, 128};
  lj1.j[1] = (GemmJob){MIXA, A1T, HA, 30, 1, 2048, 2048, 2048, 128};
  lj1.j[2] = (GemmJob){MIXV, V1T, HV, 30, 1, 2048, 2048, 2048, 128};
  lj1.j[3] = (GemmJob){MIXG, G1T, HG, 30, 2, 2048, 2048, 2048, 256};
  gemm_bt_kernel<u16><<<dim3(60,1,4), 256, 0, stream>>>(lj1);

  // 5) mid activations
  act_kernel<<<dim3(3840,1,2), 256, 0, stream>>>(HW, HG);

  // 6) LoRA second halves (bf16 C)
  GemmJobs lj2;
  lj2.j[0] = (GemmJob){HW, W2T, WL, 30, 16, 128, 128, 128, 2048};
  lj2.j[1] = (GemmJob){HA, A2T, AL, 30, 16, 128, 128, 128, 2048};
  lj2.j[2] = (GemmJob){HV, V2T, VL, 30, 16, 128, 128, 128, 2048};
  lj2.j[3] = (GemmJob){HG, G2T, GL, 30, 16, 256, 256, 256, 2048};
  gemm_bt_kernel<u16><<<dim3(480,1,4), 256, 0, stream>>>(lj2);

  // 7) post elementwise -> fp32/bf16 scan inputs (aliasing dead buffers)
  post_kernel<<<dim3(BT), 256, 0, stream>>>(
      RBUF, KBUF, VRAW, vfirst, WL, AL, VL, w0i, a0i, v0i, kki, kai, rki,
      WDEC, AF, BF, KFLO, KFHI, VSW, COEF);

  // 8) recurrence (4 blocks/head, 16-row quarters, depth-8 fp32 pipeline)
  scan_kernel<<<dim3(512), 256, 0, stream>>>(
      WDEC, RBUF, KFLO, KFHI, AF, BF, VSW, YBUF);

  // 9) GroupNorm + bonus + *g -> bf16 YG
  final_kernel<<<dim3(BT), 256, 0, stream>>>(
      YBUF, VSW, COEF, lnw, lnb, GL, YG);

  // 10) output projection (fp32 C = d_out)
  cvt_kernel<<<dim3(2048), 256, 0, stream>>>(Wo, WSLOT);
  GemmJobs oj;
  oj.j[0] = (GemmJob){YG, WSLOT, d_out, 30, 16, 2048, 2048, 2048, 2048};
  oj.j[1] = oj.j[0]; oj.j[2] = oj.j[0]; oj.j[3] = oj.j[0];
  gemm_bt_kernel<float><<<dim3(480,1,1), 256, 0, stream>>>(oj);
}

// Round 7
// 726.912 us; speedup vs baseline: 1.3576x; 1.2406x over previous
//
#include <hip/hip_runtime.h>
#include <stdint.h>

// Problem constants (B,T,C,H,N) = (4,960,2048,32,64)
#define BDIM 4
#define TDIM 960
#define CDIM 2048
#define HDIM 32
#define NDIM 64
#define BT   (BDIM*TDIM)   // 3840 rows

typedef unsigned short u16;
typedef __attribute__((ext_vector_type(8))) short short8;   // 8 bf16 (4 VGPRs)
typedef __attribute__((ext_vector_type(4))) float f32x4;
typedef __attribute__((ext_vector_type(2))) float f32x2;

__device__ __forceinline__ float b2f(u16 u){
  union{unsigned int i; float f;}x; x.i=((unsigned int)u)<<16; return x.f;
}
__device__ __forceinline__ u16 f2b(float f){
  union{float f; unsigned int i;}x; x.f=f;
  unsigned int r = x.i + 0x7fffu + ((x.i>>16)&1u);   // RNE
  return (u16)(r>>16);
}
__device__ __forceinline__ unsigned pk2(float lo, float hi){
  return (unsigned)f2b(lo) | ((unsigned)f2b(hi)<<16);
}
__device__ __forceinline__ void unpack8(uint4 p, float* o){
  o[0]=b2f((u16)(p.x&0xffff)); o[1]=b2f((u16)(p.x>>16));
  o[2]=b2f((u16)(p.y&0xffff)); o[3]=b2f((u16)(p.y>>16));
  o[4]=b2f((u16)(p.z&0xffff)); o[5]=b2f((u16)(p.z>>16));
  o[6]=b2f((u16)(p.w&0xffff)); o[7]=b2f((u16)(p.w>>16));
}
__device__ __forceinline__ uint4 pack8(const float* o){
  uint4 p;
  p.x = pk2(o[0],o[1]);
  p.y = pk2(o[2],o[3]);
  p.z = pk2(o[4],o[5]);
  p.w = pk2(o[6],o[7]);
  return p;
}
__device__ __forceinline__ void ld8f(const float* p, float* o){
  float4 a = *(const float4*)p;
  float4 b = *(const float4*)(p+4);
  o[0]=a.x;o[1]=a.y;o[2]=a.z;o[3]=a.w;o[4]=b.x;o[5]=b.y;o[6]=b.z;o[7]=b.w;
}
__device__ __forceinline__ float sigm(float x){ return 1.f/(1.f+expf(-x)); }
__device__ __forceinline__ void stc(float* p, float v){ *p = v; }
__device__ __forceinline__ void stc(u16* p, float v){ *p = f2b(v); }
__device__ __forceinline__ f32x2 lo2(f32x4 v){ return __builtin_shufflevector(v, v, 0, 1); }
__device__ __forceinline__ f32x2 hi2(f32x4 v){ return __builtin_shufflevector(v, v, 2, 3); }
// packed-bf16 word -> f32x2 {lo,hi}: lo = w<<16, hi = w&0xffff0000 (already a float)
__device__ __forceinline__ f32x2 up2(unsigned w){
  return (f32x2){ __int_as_float((int)(w<<16)), __int_as_float((int)(w & 0xffff0000u)) };
}

// 16-lane butterfly sum on the VALU pipe (DPP), zero LDS traffic.
__device__ __forceinline__ float row_red16(float x){
  x += __int_as_float(__builtin_amdgcn_update_dpp(0, __float_as_int(x), 0xB1,  0xF, 0xF, true));
  x += __int_as_float(__builtin_amdgcn_update_dpp(0, __float_as_int(x), 0x4E,  0xF, 0xF, true));
  x += __int_as_float(__builtin_amdgcn_update_dpp(0, __float_as_int(x), 0x141, 0xF, 0xF, true));
  x += __int_as_float(__builtin_amdgcn_update_dpp(0, __float_as_int(x), 0x140, 0xF, 0xF, true));
  return x;
}

// ---------------------------------------------------------------------------
// 0) fp32 -> bf16 weight conversion, up to 3 matrices per launch (z-indexed)
struct CvtJobs { const float* s[3]; u16* d[3]; };
__global__ __launch_bounds__(256) void cvt_kernel(CvtJobs jobs){
  const float* src = jobs.s[blockIdx.z];
  u16* dst = jobs.d[blockIdx.z];
  size_t i = ((size_t)blockIdx.x*256 + threadIdx.x)*8;
  float v[8]; ld8f(src+i, v);
  *(uint4*)(dst+i) = pack8(v);
}

// ---------------------------------------------------------------------------
// 1) batched transpose+pad+cvt for LoRA weights (tiny: <6 MB total)
struct TJob { const float* src; u16* dst; int R, Cs, DR, DC; };
struct TJobs8 { TJob j[8]; };

__global__ __launch_bounds__(256) void transpose_pad_kernel(TJobs8 jobs){
  TJob jb = jobs.j[blockIdx.z];
  int idx = blockIdx.x*256 + threadIdx.x;
  int total = jb.DR*jb.DC;
  if (idx >= total) return;
  int i = idx / jb.DC, k = idx % jb.DC;
  float v = 0.f;
  if (i < jb.Cs && k < jb.R) v = jb.src[(size_t)k*jb.Cs + i];
  jb.dst[idx] = f2b(v);
}

// ---------------------------------------------------------------------------
// 2) token-shift mixes: m = x + (x_prev - x)*coef  (6 bf16 outputs)
__global__ __launch_bounds__(256) void mix_kernel(
  const float* x,
  const float* cr, const float* cw, const float* ck,
  const float* cv, const float* ca, const float* cg,
  u16* mr, u16* mw, u16* mk, u16* mv, u16* ma, u16* mg)
{
  size_t tid = (size_t)blockIdx.x*256 + threadIdx.x;
  size_t base = tid*8;
  int c = (int)(base % CDIM);
  int row = (int)(base / CDIM);
  int t = row % TDIM;
  float xc[8], xp[8], xx[8], cf[8], o[8];
  ld8f(x+base, xc);
  if (t > 0) {
    ld8f(x+base-CDIM, xp);
  } else {
    for(int j=0;j<8;j++) xp[j]=0.f;
  }
  #pragma unroll
  for(int j=0;j<8;j++) xx[j]=xp[j]-xc[j];
#define DOMIX(CP, OP) do { ld8f(CP+c, cf); \
  _Pragma("unroll") for(int j=0;j<8;j++) o[j]=xc[j]+xx[j]*cf[j]; \
  *(uint4*)(OP+base)=pack8(o); } while(0)
  DOMIX(cr, mr); DOMIX(cw, mw); DOMIX(ck, mk);
  DOMIX(cv, mv); DOMIX(ca, ma); DOMIX(cg, mg);
#undef DOMIX
}

// ---------------------------------------------------------------------------
// 3) bf16 GEMM, C[M,N] = A[M,K] * Bt[N,K]^T  (B^T layout, m97 structure)
// 128x128 tile, BK=64, 256 threads. Up to 8 z-indexed jobs per launch
// (blocks with bn >= nbn early-exit, so jobs of different sizes batch fine).
struct GemmJob {
  const u16* A; const u16* Bt; void* C;
  int nbm, nbn, K, lda, ldb, ldc;
};
struct GemmJobs8 { GemmJob j[8]; };

template<typename TC>
__global__ __launch_bounds__(256, 2) void gemm_bt_kernel(GemmJobs8 jobs){
  GemmJob jb = jobs.j[blockIdx.z];
  int bm = blockIdx.x % jb.nbm;
  int bn = blockIdx.x / jb.nbm;
  if (bn >= jb.nbn) return;
  __shared__ __attribute__((aligned(16))) u16 As[128*64];
  __shared__ __attribute__((aligned(16))) u16 Bs[128*64];
  int tid = threadIdx.x;
  int wave = tid>>6, lane = tid&63;
  int wr = wave>>1, wc = wave&1;
  f32x4 acc[4][4];
  #pragma unroll
  for(int i=0;i<4;i++)
    #pragma unroll
    for(int j=0;j<4;j++) acc[i][j] = (f32x4){0.f,0.f,0.f,0.f};
  const int rA0 = bm*128;
  const int rB0 = bn*128;
  int srow = (lane>>3);        // 0..7 row within 8-row slab
  int scol = (lane&7)*8;       // k element offset (8 bf16 = 16B)
  for (int k0=0; k0<jb.K; k0+=64){
    #pragma unroll
    for (int it=0; it<4; ++it){
      int rr = wave*32 + it*8;  // wave-uniform
      const u16* gA = jb.A + (size_t)(rA0 + rr + srow)*jb.lda + (k0 + scol);
      __builtin_amdgcn_global_load_lds((const __attribute__((address_space(1))) void*)gA,
          (__attribute__((address_space(3))) void*)&As[rr*64], 16, 0, 0);
      const u16* gB = jb.Bt + (size_t)(rB0 + rr + srow)*jb.ldb + (k0 + scol);
      __builtin_amdgcn_global_load_lds((const __attribute__((address_space(1))) void*)gB,
          (__attribute__((address_space(3))) void*)&Bs[rr*64], 16, 0, 0);
    }
    __syncthreads();   // compiler emits vmcnt(0) drain before s_barrier
    #pragma unroll
    for (int kc=0; kc<2; ++kc){
      short8 af[4], bfr[4];
      int ko = kc*32 + (lane>>4)*8;
      #pragma unroll
      for (int mi=0; mi<4; ++mi)
        af[mi] = *(const short8*)&As[(wr*64 + mi*16 + (lane&15))*64 + ko];
      #pragma unroll
      for (int ni=0; ni<4; ++ni)
        bfr[ni] = *(const short8*)&Bs[(wc*64 + ni*16 + (lane&15))*64 + ko];
      #pragma unroll
      for (int mi=0; mi<4; ++mi)
        #pragma unroll
        for (int ni=0; ni<4; ++ni)
          acc[mi][ni] = __builtin_amdgcn_mfma_f32_16x16x32_bf16(af[mi], bfr[ni], acc[mi][ni], 0, 0, 0);
    }
    __syncthreads();
  }
  // epilogue: C/D layout col=lane&15, row=(lane>>4)*4+reg  [m89/m91 verified]
  TC* C = (TC*)jb.C;
  int cn = (lane&15);
  int rq = (lane>>4)*4;
  #pragma unroll
  for (int mi=0; mi<4; ++mi){
    #pragma unroll
    for (int ni=0; ni<4; ++ni){
      int col = rB0 + wc*64 + ni*16 + cn;
      int row = rA0 + wr*64 + mi*16 + rq;
      #pragma unroll
      for (int e=0; e<4; ++e)
        stc(&C[(size_t)(row+e)*jb.ldc + col], acc[mi][ni][e]);
    }
  }
}

// ---------------------------------------------------------------------------
// 4) mid-LoRA activations: tanh on hw, sigmoid on hg (pads stay 0 -> tanh(0)=0)
__global__ __launch_bounds__(256) void act_kernel(u16* hw, u16* hg){
  int idx = blockIdx.x*256 + threadIdx.x;
  if (blockIdx.z==0){ if (idx < BT*128) hw[idx] = f2b(tanhf(b2f(hw[idx]))); }
  else              { if (idx < BT*256) hg[idx] = f2b(sigm(b2f(hg[idx]))); }
}

// ---------------------------------------------------------------------------
// 5) post-GEMM elementwise: w decay, a/v finals, kk normalize, k scale
// Outputs for the scan: DECAY fp32, QKI = interleaved {q01,k01} 8B entries
// per colpair, ABI = interleaved {a01,b01}, VS bf16 (written in-place over
// the dead RBUF plane; same-thread read-then-write, no cross-thread hazard).
__global__ __launch_bounds__(256) void post_kernel(
  const u16* rbuf, const u16* kbuf, const u16* vraw, const float* vfirst,
  const u16* wl, const u16* al, const u16* vl,
  const float* w0, const float* a0, const float* v0,
  const float* kkc, const float* kac,
  float* dout, uint4* qki, uint4* abi, u16* vs)
{
  int row = blockIdx.x, tid = threadIdx.x;
  int c = tid*8;
  size_t base = (size_t)row*CDIM + c;
  float qf[8], kf[8], vr[8], vf[8], wlf[8], alf[8], vlf[8], w0f[8], a0f[8], v0f[8], kkf[8], kaf[8];
  unpack8(*(const uint4*)(rbuf+base), qf);
  unpack8(*(const uint4*)(kbuf+base), kf);
  unpack8(*(const uint4*)(vraw+base), vr);
  ld8f(vfirst+base, vf);
  unpack8(*(const uint4*)(wl+base), wlf);
  unpack8(*(const uint4*)(al+base), alf);
  unpack8(*(const uint4*)(vl+base), vlf);
  ld8f(w0+c, w0f);
  ld8f(a0+c, a0f);
  ld8f(v0+c, v0f);
  ld8f(kkc+c, kkf);
  ld8f(kac+c, kaf);
  float dv[8], av[8], vv[8], kkr[8], kfin[8], asv[8], bsv[8];
  float ssq = 0.f;
  #pragma unroll
  for (int j=0;j<8;j++){
    float wv = -log1pf(expf(-(w0f[j]+wlf[j]))) - 0.5f;       // -softplus(-z)-0.5
    dv[j]  = expf(-expf(wv));                                // decay
    av[j]  = sigm(a0f[j]+alf[j]);
    vv[j]  = vr[j] + (vf[j]-vr[j])*sigm(v0f[j]+vlf[j]);
    kkr[j] = kf[j]*kkf[j];
    ssq   += kkr[j]*kkr[j];
    kfin[j]= kf[j]*(1.f + (av[j]-1.f)*kaf[j]);
  }
  // head = 8 consecutive lanes (thread covers 8 contiguous c, head = 64 c)
  ssq += __shfl_xor(ssq,1); ssq += __shfl_xor(ssq,2); ssq += __shfl_xor(ssq,4);
  float inv = 1.f/fmaxf(sqrtf(ssq), 1e-12f);
  #pragma unroll
  for (int j=0;j<8;j++){ float kkn = kkr[j]*inv; asv[j] = -kkn; bsv[j] = kkn*av[j]; }
  *(float4*)(dout+base)   = make_float4(dv[0],dv[1],dv[2],dv[3]);
  *(float4*)(dout+base+4) = make_float4(dv[4],dv[5],dv[6],dv[7]);
  // interleaved q/k and a/b: 8B entry per colpair, byte off = row*8192 + c*4
  uint4* qke = (uint4*)((char*)qki + (size_t)row*8192 + (size_t)c*4);
  qke[0] = make_uint4(pk2(qf[0],qf[1]), pk2(kfin[0],kfin[1]), pk2(qf[2],qf[3]), pk2(kfin[2],kfin[3]));
  qke[1] = make_uint4(pk2(qf[4],qf[5]), pk2(kfin[4],kfin[5]), pk2(qf[6],qf[7]), pk2(kfin[6],kfin[7]));
  uint4* abe = (uint4*)((char*)abi + (size_t)row*8192 + (size_t)c*4);
  abe[0] = make_uint4(pk2(asv[0],asv[1]), pk2(bsv[0],bsv[1]), pk2(asv[2],asv[3]), pk2(bsv[2],bsv[3]));
  abe[1] = make_uint4(pk2(asv[4],asv[5]), pk2(bsv[4],bsv[5]), pk2(asv[6],asv[7]), pk2(bsv[6],bsv[7]));
  *(uint4*)(vs+base) = pack8(vv);   // vs aliases rbuf: in-thread read-then-write
}

// ---------------------------------------------------------------------------
// 6) the linear recurrence. Rows of S evolve independently:
//    S_t[i,:] = S_{t-1}[i,:]*(diag(d)+a b^T) + v_i k^T
// Round-7: the round-4 structure UNCHANGED (512 blocks, 4/head, 16-lane col
// groups, 4 cols/thread, pure-DPP reduction, depth-8 named 13-VGPR records,
// sched_barrier fences, launch_bounds(256,2) — the only config where the
// pipeline provably survives, VGPR 112). Only dostep changes: state as two
// f32x2 and packed-f32 ops (v_pk_fma_f32), halving FMA-class instructions.
// Unpack of packed-bf16 words is 2 inst/pair (lo = w<<16; hi = w&0xffff0000).
__global__ __launch_bounds__(256, 2) void scan_kernel(
  const float* __restrict__ decayp, const uint4* __restrict__ qki,
  const uint4* __restrict__ abi, const u16* __restrict__ vs,
  float* __restrict__ yb)
{
  int blk = blockIdx.x;          // b*128 + h*4 + qtr
  int b    = blk >> 7;
  int h    = (blk >> 2) & 31;
  int qtr  = blk & 3;
  int tid  = threadIdx.x;
  int jg   = tid & 15;           // col group (4 cols)
  int ii   = tid >> 4;           // row within quarter (0..15)
  int row  = qtr*16 + ii;

  const char* dP = (const char*)decayp + (size_t)b*TDIM*8192 + h*256 + jg*16;
  const char* qP = (const char*)qki    + (size_t)b*TDIM*8192 + h*256 + jg*16;
  const char* aP = (const char*)abi    + (size_t)b*TDIM*8192 + h*256 + jg*16;
  const char* vP = (const char*)vs     + (size_t)b*TDIM*4096 + h*128 + row*2;

  f32x2 Sa = (f32x2){0.f,0.f}, Sb = (f32x2){0.f,0.f};

  struct SR { f32x4 d; uint4 qk; uint4 ab; u16 v; };   // 13 VGPRs
  auto ld = [&](int t)->SR{
    SR r; size_t o = (size_t)t*8192;
    r.d  = *(const f32x4*)(dP + o);
    r.qk = *(const uint4*)(qP + o);
    r.ab = *(const uint4*)(aP + o);
    r.v  = *(const u16*)(vP + (size_t)t*4096);
    return r;
  };
  auto dostep = [&](const SR& r)->float{
    f32x2 a01 = up2(r.ab.x), a23 = up2(r.ab.z);
    f32x2 t = Sa*a01 + Sb*a23;                 // pk mul + pk fma
    float sap = t[0] + t[1];
    sap = row_red16(sap);                      // pure-VALU butterfly
    f32x2 b01 = up2(r.ab.y), b23 = up2(r.ab.w);
    f32x2 k01 = up2(r.qk.y), k23 = up2(r.qk.w);
    float vi = b2f(r.v);
    f32x2 s2 = (f32x2){sap, sap};
    f32x2 v2 = (f32x2){vi, vi};
    Sa = Sa*lo2(r.d) + s2*b01 + v2*k01;        // 3 pk ops
    Sb = Sb*hi2(r.d) + s2*b23 + v2*k23;        // 3 pk ops
    f32x2 q01 = up2(r.qk.x), q23 = up2(r.qk.z);
    f32x2 u = Sa*q01 + Sb*q23;                 // pk mul + pk fma
    return u[0] + u[1];
  };

  SR A0=ld(0), A1=ld(1), A2=ld(2), A3=ld(3), A4=ld(4), A5=ld(5), A6=ld(6), A7=ld(7);
  for (int g=0; g<120; ++g){
    int tn = g*8 + 8;
    float yp[8];
#define STEPR(AR, S_) { yp[S_] = dostep(AR); int t_ = tn + (S_); \
    AR = ld(t_ < TDIM ? t_ : TDIM-1); }
    STEPR(A0,0) STEPR(A1,1) __builtin_amdgcn_sched_barrier(0);
    STEPR(A2,2) STEPR(A3,3) __builtin_amdgcn_sched_barrier(0);
    STEPR(A4,4) STEPR(A5,5) __builtin_amdgcn_sched_barrier(0);
    STEPR(A6,6) STEPR(A7,7) __builtin_amdgcn_sched_barrier(0);
#undef STEPR
    // deferred y reductions: 8 independent DPP butterflies, 8 lanes store
    #pragma unroll
    for (int s=0; s<8; ++s) yp[s] = row_red16(yp[s]);
    if (jg < 8){
      float out = 0.f;
      #pragma unroll
      for (int s=0; s<8; ++s) if (jg==s) out = yp[s];   // static idx (no scratch)
      yb[(size_t)b*TDIM*CDIM + (size_t)(g*8+jg)*CDIM + h*NDIM + row] = out;
    }
  }
}

// ---------------------------------------------------------------------------
// 7) GroupNorm + bonus term + *g  -> bf16 YG (input of the final GEMM)
// r and k come interleaved from QKI; v from the relocated VS plane.
__global__ __launch_bounds__(256) void final_kernel(
  const float* yb, const uint4* qki, const u16* vs,
  const float* rk, const float* lnw, const float* lnb, const u16* gl, u16* yg)
{
  int row = blockIdx.x, tid = threadIdx.x;
  int c = tid*8;
  size_t base = (size_t)row*CDIM + c;
  float y[8], rf[8], kf[8], vf[8], rkf[8], lw[8], lb[8], gf[8];
  ld8f(yb+base, y);
  const uint4* qke = (const uint4*)((const char*)qki + (size_t)row*8192 + (size_t)c*4);
  uint4 e0 = qke[0], e1 = qke[1];
  rf[0]=b2f((u16)(e0.x&0xffff)); rf[1]=b2f((u16)(e0.x>>16));
  rf[2]=b2f((u16)(e0.z&0xffff)); rf[3]=b2f((u16)(e0.z>>16));
  rf[4]=b2f((u16)(e1.x&0xffff)); rf[5]=b2f((u16)(e1.x>>16));
  rf[6]=b2f((u16)(e1.z&0xffff)); rf[7]=b2f((u16)(e1.z>>16));
  kf[0]=b2f((u16)(e0.y&0xffff)); kf[1]=b2f((u16)(e0.y>>16));
  kf[2]=b2f((u16)(e0.w&0xffff)); kf[3]=b2f((u16)(e0.w>>16));
  kf[4]=b2f((u16)(e1.y&0xffff)); kf[5]=b2f((u16)(e1.y>>16));
  kf[6]=b2f((u16)(e1.w&0xffff)); kf[7]=b2f((u16)(e1.w>>16));
  unpack8(*(const uint4*)(vs+base), vf);
  ld8f(rk+c,  rkf);   // r_k is [H*N]=[C] flat
  ld8f(lnw+c, lw);
  ld8f(lnb+c, lb);
  unpack8(*(const uint4*)(gl+base), gf);
  float sy=0.f, syy=0.f, coef=0.f;
  #pragma unroll
  for (int j=0;j<8;j++){ sy+=y[j]; syy+=y[j]*y[j]; coef += rf[j]*kf[j]*rkf[j]; }
  sy  += __shfl_xor(sy,1);  sy  += __shfl_xor(sy,2);  sy  += __shfl_xor(sy,4);
  syy += __shfl_xor(syy,1); syy += __shfl_xor(syy,2); syy += __shfl_xor(syy,4);
  coef+= __shfl_xor(coef,1);coef+= __shfl_xor(coef,2);coef+= __shfl_xor(coef,4);
  float mu  = sy*(1.f/64.f);
  float var = syy*(1.f/64.f) - mu*mu;
  float rs  = rsqrtf(var + 6.4e-4f);    // EPS_GN = 1e-5*64
  float o[8];
  #pragma unroll
  for (int j=0;j<8;j++)
    o[j] = (((y[j]-mu)*rs)*lw[j] + lb[j] + coef*vf[j]) * gf[j];
  *(uint4*)(yg+base) = pack8(o);
}

// ---------------------------------------------------------------------------
extern "C" void kernel_launch(void* const* d_in, const int* in_sizes, int n_in,
                              void* d_out, int out_size, void* d_ws, size_t ws_size,
                              hipStream_t stream)
{
  const float* x      = (const float*)d_in[0];
  const float* vfirst = (const float*)d_in[1];
  const float* c_r = (const float*)d_in[2];
  const float* c_w = (const float*)d_in[3];
  const float* c_k = (const float*)d_in[4];
  const float* c_v = (const float*)d_in[5];
  const float* c_a = (const float*)d_in[6];
  const float* c_g = (const float*)d_in[7];
  const float* w0i = (const float*)d_in[8];
  const float* w1i = (const float*)d_in[9];
  const float* w2i = (const float*)d_in[10];
  const float* a0i = (const float*)d_in[11];
  const float* a1i = (const float*)d_in[12];
  const float* a2i = (const float*)d_in[13];
  const float* v0i = (const float*)d_in[14];
  const float* v1i = (const float*)d_in[15];
  const float* v2i = (const float*)d_in[16];
  const float* g1i = (const float*)d_in[17];
  const float* g2i = (const float*)d_in[18];
  const float* kki = (const float*)d_in[19];
  const float* kai = (const float*)d_in[20];
  const float* rki = (const float*)d_in[21];
  const float* Wr  = (const float*)d_in[22];
  const float* Wk  = (const float*)d_in[23];
  const float* Wv  = (const float*)d_in[24];
  const float* Wo  = (const float*)d_in[25];
  const float* lnw = (const float*)d_in[26];
  const float* lnb = (const float*)d_in[27];

  char* ws = (char*)d_ws;
  const size_t S2 = (size_t)BT*CDIM*2;    // bf16 [BT,C] plane = 15,728,640 B
  // bf16 mix planes [0, 6*S2)  (later aliased by scan inputs)
  u16* MIXR = (u16*)(ws + 0*S2);
  u16* MIXW = (u16*)(ws + 1*S2);
  u16* MIXK = (u16*)(ws + 2*S2);
  u16* MIXV = (u16*)(ws + 3*S2);
  u16* MIXA = (u16*)(ws + 4*S2);
  u16* MIXG = (u16*)(ws + 5*S2);
  // bf16 projection outputs
  u16* RBUF = (u16*)(ws + 6*S2);
  u16* KBUF = (u16*)(ws + 7*S2);
  u16* VRAW = (u16*)(ws + 8*S2);
  // weight slot (Wr, later Wo)
  char* WB = ws + 9*S2;
  u16* WSLOT = (u16*)WB;            // 2048*2048*2 = 8,388,608 B
  char* WT = WB + 8388608;
  u16* W1T = (u16*)(WT + 0);        // [128,2048]
  u16* A1T = (u16*)(WT + 524288);
  u16* V1T = (u16*)(WT + 1048576);
  u16* G1T = (u16*)(WT + 1572864);  // [256,2048]
  u16* W2T = (u16*)(WT + 2621440);  // [2048,128]
  u16* A2T = (u16*)(WT + 3145728);
  u16* V2T = (u16*)(WT + 3670016);
  u16* G2T = (u16*)(WT + 4194304);  // [2048,256]
  char* HB = WT + 5242880;
  u16* HW = (u16*)(HB + 0);         // [BT,128]
  u16* HA = (u16*)(HB + 983040);
  u16* HV = (u16*)(HB + 1966080);
  u16* HG = (u16*)(HB + 2949120);   // [BT,256]
  char* L2 = HB + 4915200;
  u16* WL = (u16*)(L2 + 0*S2);
  u16* AL = (u16*)(L2 + 1*S2);
  u16* VL = (u16*)(L2 + 2*S2);
  u16* GL = (u16*)(L2 + 3*S2);      // ws end = L2 + 4*S2 = 223,019,008 B (~212.7 MiB)
  // transient extra weight slots for the fused rkv GEMM launch: live only
  // between cvt3 and the mega-GEMM; WL/AL (their footprint) are written
  // strictly later (lj2).
  u16* WK2 = (u16*)(L2 + 0);            // 8.4 MB over WL..
  u16* WV2 = (u16*)(L2 + 8388608);      // 8.4 MB over ..AL
  // aliases (producers strictly after last consumer of the dead buffers):
  float* WDEC = (float*)(ws + 0*S2);    // fp32 decay over MIXR+MIXW
  uint4* QKI  = (uint4*)(ws + 2*S2);    // interleaved q/k pairs over MIXK+MIXV
  uint4* ABI  = (uint4*)(ws + 4*S2);    // interleaved a/b pairs over MIXA+MIXG
  u16*   VS6  = (u16*)(ws + 6*S2);      // v bf16 over RBUF (post: in-thread r/w)
  float* YBUF = (float*)(L2 + 0*S2);    // fp32 over WL+AL (after post consumed them)
  u16* YG = (u16*)(L2 + 2*S2);          // over VL
  (void)in_sizes; (void)n_in; (void)out_size; (void)ws_size;

  // 1) transpose+pad+cvt LoRA weights
  TJobs8 tj;
  tj.j[0] = (TJob){w1i, W1T, 2048,  96, 128, 2048};
  tj.j[1] = (TJob){a1i, A1T, 2048,  96, 128, 2048};
  tj.j[2] = (TJob){v1i, V1T, 2048,  64, 128, 2048};
  tj.j[3] = (TJob){g1i, G1T, 2048, 256, 256, 2048};
  tj.j[4] = (TJob){w2i, W2T,   96, 2048, 2048, 128};
  tj.j[5] = (TJob){a2i, A2T,   96, 2048, 2048, 128};
  tj.j[6] = (TJob){v2i, V2T,   64, 2048, 2048, 128};
  tj.j[7] = (TJob){g2i, G2T,  256, 2048, 2048, 256};
  transpose_pad_kernel<<<dim3(2048,1,8), 256, 0, stream>>>(tj);

  // 2) token-shift mixes (fp32 in, bf16 out)
  mix_kernel<<<dim3(BT*CDIM/8/256), 256, 0, stream>>>(
      x, c_r, c_w, c_k, c_v, c_a, c_g, MIXR, MIXW, MIXK, MIXV, MIXA, MIXG);

  // 3) one cvt launch for all three projection weights
  CvtJobs cj;
  cj.s[0] = Wr; cj.d[0] = WSLOT;
  cj.s[1] = Wk; cj.d[1] = WK2;
  cj.s[2] = Wv; cj.d[2] = WV2;
  cvt_kernel<<<dim3(2048,1,3), 256, 0, stream>>>(cj);

  // 4) fused GEMM launch: r,k,v projections + all 4 LoRA first halves
  //    (7 z-jobs, 480 x-blocks; small jobs early-exit surplus blocks)
  GemmJobs8 mj;
  mj.j[0] = (GemmJob){MIXR, WSLOT, RBUF, 30, 16, 2048, 2048, 2048, 2048};
  mj.j[1] = (GemmJob){MIXK, WK2,   KBUF, 30, 16, 2048, 2048, 2048, 2048};
  mj.j[2] = (GemmJob){MIXV, WV2,   VRAW, 30, 16, 2048, 2048, 2048, 2048};
  mj.j[3] = (GemmJob){MIXW, W1T, HW, 30, 1, 2048, 2048, 2048, 128};
  mj.j[4] = (GemmJob){MIXA, A1T, HA, 30, 1, 2048, 2048, 2048, 128};
  mj.j[5] = (GemmJob){MIXV, V1T, HV, 30, 1, 2048, 2048, 2048, 128};
  mj.j[6] = (GemmJob){MIXG, G1T, HG, 30, 2, 2048, 2048, 2048, 256};
  mj.j[7] = mj.j[0];   // unused (grid z = 7)
  gemm_bt_kernel<u16><<<dim3(480,1,7), 256, 0, stream>>>(mj);

  // 5) mid activations
  act_kernel<<<dim3(3840,1,2), 256, 0, stream>>>(HW, HG);

  // 6) LoRA second halves (bf16 C)
  GemmJobs8 lj2;
  lj2.j[0] = (GemmJob){HW, W2T, WL, 30, 16, 128, 128, 128, 2048};
  lj2.j[1] = (GemmJob){HA, A2T, AL, 30, 16, 128, 128, 128, 2048};
  lj2.j[2] = (GemmJob){HV, V2T, VL, 30, 16, 128, 128, 128, 2048};
  lj2.j[3] = (GemmJob){HG, G2T, GL, 30, 16, 256, 256, 256, 2048};
  lj2.j[4] = lj2.j[0]; lj2.j[5] = lj2.j[0]; lj2.j[6] = lj2.j[0]; lj2.j[7] = lj2.j[0];
  gemm_bt_kernel<u16><<<dim3(480,1,4), 256, 0, stream>>>(lj2);

  // 7) post elementwise -> scan inputs (write into dead mix planes)
  post_kernel<<<dim3(BT), 256, 0, stream>>>(
      RBUF, KBUF, VRAW, vfirst, WL, AL, VL, w0i, a0i, v0i, kki, kai,
      WDEC, QKI, ABI, VS6);

  // 8) recurrence (4 blocks/head, 16-row quarters, depth-8 reg pipeline)
  scan_kernel<<<dim3(512), 256, 0, stream>>>(
      WDEC, QKI, ABI, VS6, YBUF);

  // 9) GroupNorm + bonus + *g -> bf16 YG
  final_kernel<<<dim3(BT), 256, 0, stream>>>(
      YBUF, QKI, VS6, rki, lnw, lnb, GL, YG);

  // 10) output projection (fp32 C = d_out)
  CvtJobs co;
  co.s[0] = Wo; co.d[0] = WSLOT;
  co.s[1] = Wo; co.d[1] = WSLOT;
  co.s[2] = Wo; co.d[2] = WSLOT;
  cvt_kernel<<<dim3(2048,1,1), 256, 0, stream>>>(co);
  GemmJobs8 oj;
  oj.j[0] = (GemmJob){YG, WSLOT, d_out, 30, 16, 2048, 2048, 2048, 2048};
  for (int i=1;i<8;i++) oj.j[i] = oj.j[0];
  gemm_bt_kernel<float><<<dim3(480,1,1), 256, 0, stream>>>(oj);
}